// Round 8
// baseline (131.833 us; speedup 1.0000x reference)
//
#include <hip/hip_runtime.h>

// Problem constants
#define NL 64
#define NR 4096
#define NE 32
#define NF 64
#define NP 8

// RBF math:  rbf = exp(-((d - mu_e)*3.2)^2) = exp2(-(d*DSCALE - e*MUSTEP)^2)
#define DSCALE 3.8435917081166390f   // 3.2 * sqrt(log2(e))
#define MUSTEP 1.2398683f            // (10/31) * DSCALE
#define EPS3   3e-10f                // eps added per coordinate (3 coords)

typedef _Float16 f16x8 __attribute__((ext_vector_type(8)));
typedef __fp16   h16x2 __attribute__((ext_vector_type(2)));   // cvt_pkrtz result
typedef float    f32x4 __attribute__((ext_vector_type(4)));

#define NBLK  1024                   // 256 r-blocks x 4 e-blocks
#define MAGIC 0xC0FFEE01u

// LDS map (24832 B -> LDS-capacity 6 blocks/CU; grid gives 4/CU):
//   REC   [8 e][16 r][128 B swz]   @ 0     : 16384 B, byte-in-row = (8*fq)^((r&7)*16)
//   COORD [64 l][8 p][4 f32]       @ 16384 :  8192 B (dead after dists; wred alias)
#define REC_B   0
#define COORD_B 16384

// ws layout: [0, 32KiB) = partials float[8][NBLK] ; [32KiB, +4KiB) = flags u32[NBLK]
__global__ __launch_bounds__(256, 4)
void ff_main(const float* __restrict__ lig_feat,    // [64][32][64]
             const float* __restrict__ rec_feat,    // [4096][32][64]
             const float* __restrict__ lig_coords,  // [8][64][3]
             const float* __restrict__ rec_coord,   // [4096][3]
             const float* __restrict__ wq,          // weight scalar
             const float* __restrict__ bq,          // bias scalar
             float* __restrict__ ws,                // workspace
             float* __restrict__ out)               // [8]
{
    __shared__ __align__(16) char smem[24832];

    const int t    = threadIdx.x;
    const int bid  = blockIdx.x;
    const int rb   = bid & 255;
    const int eb   = bid >> 8;
    const int r0   = rb * 16;
    const int e0   = eb * 8;
    const int lane = t & 63;
    const int wv   = t >> 6;
    const int l0   = wv * 16;
    const int cn   = lane & 15;       // MFMA col / frag row
    const int kg   = lane >> 4;       // k-group 0..3

    unsigned* flags = (unsigned*)((char*)ws + 32768);

    // ---- phase 1a: stage lig coords -> LDS [l][p][4] ----
#pragma unroll
    for (int j = 0; j < 6; ++j) {
        const int s = j * 256 + t;            // 0..1535 over [8p][64l][3c]
        const int p = s / 192;
        const int rem = s - p * 192;
        const int l = rem / 3, c = rem - l * 3;
        *(float*)(smem + COORD_B + (l * 8 + p) * 16 + c * 4) = lig_coords[s];
    }
    // ---- phase 1b: stage rec feat tile -> LDS fp16 swizzled ----
    const int srow = t >> 4, sfq = t & 15;
    const int rswz = (8 * sfq) ^ ((srow & 7) << 4);
#pragma unroll
    for (int e = 0; e < 8; ++e) {
        const float4 v = *(const float4*)&rec_feat[((r0 + srow) * NE + e0 + e) * NF + sfq * 4];
        union { h16x2 h[2]; uint2 u; } pk;
        pk.h[0] = __builtin_amdgcn_cvt_pkrtz(v.x, v.y);
        pk.h[1] = __builtin_amdgcn_cvt_pkrtz(v.z, v.w);
        *(uint2*)(smem + REC_B + e * 2048 + srow * 128 + rswz) = pk.u;
    }
    __syncthreads();   // coords + rec tile ready

    // ---- phase 2: this lane's 32 distances in registers (no duplication:
    //      4 waves x 64 lanes x (4 l x 1 r) covers the 64x16 tile exactly) ----
    const int rr = r0 + cn;
    const float rx = rec_coord[rr * 3 + 0];
    const float ry = rec_coord[rr * 3 + 1];
    const float rz = rec_coord[rr * 3 + 2];
    float ds[4][NP];
#pragma unroll
    for (int reg = 0; reg < 4; ++reg) {
        const int l = l0 + kg * 4 + reg;
#pragma unroll
        for (int p = 0; p < NP; ++p) {
            const float4 lc = *(const float4*)(smem + COORD_B + (l * 8 + p) * 16);
            const float dx = lc.x - rx, dy = lc.y - ry, dz = lc.z - rz;
            const float d2 = fmaf(dx, dx, fmaf(dy, dy, fmaf(dz, dz, EPS3)));
            ds[reg][p] = __builtin_amdgcn_sqrtf(d2) * DSCALE;
        }
    }

    // ---- phase 3: main loop over 8 e's ----
    const int bsw = (cn & 7) << 4;
    const int b0o = REC_B + cn * 128 + ((kg * 16) ^ bsw);
    const int b1o = REC_B + cn * 128 + ((kg * 16 + 64) ^ bsw);
    const float* ligb = &lig_feat[((l0 + cn) * NE + e0) * NF + kg * 8];

    float U[NP];
#pragma unroll
    for (int p = 0; p < NP; ++p) U[p] = 0.f;

#pragma unroll
    for (int ee = 0; ee < 8; ++ee) {
        const float4 af0 = *(const float4*)(ligb + ee * NF + 0);
        const float4 af1 = *(const float4*)(ligb + ee * NF + 4);
        const float4 af2 = *(const float4*)(ligb + ee * NF + 32);
        const float4 af3 = *(const float4*)(ligb + ee * NF + 36);
        union { h16x2 h[4]; f16x8 v; } a0, a1;
        a0.h[0] = __builtin_amdgcn_cvt_pkrtz(af0.x, af0.y);
        a0.h[1] = __builtin_amdgcn_cvt_pkrtz(af0.z, af0.w);
        a0.h[2] = __builtin_amdgcn_cvt_pkrtz(af1.x, af1.y);
        a0.h[3] = __builtin_amdgcn_cvt_pkrtz(af1.z, af1.w);
        a1.h[0] = __builtin_amdgcn_cvt_pkrtz(af2.x, af2.y);
        a1.h[1] = __builtin_amdgcn_cvt_pkrtz(af2.z, af2.w);
        a1.h[2] = __builtin_amdgcn_cvt_pkrtz(af3.x, af3.y);
        a1.h[3] = __builtin_amdgcn_cvt_pkrtz(af3.z, af3.w);
        const f16x8 b0 = *(const f16x8*)(smem + b0o + ee * 2048);
        const f16x8 b1 = *(const f16x8*)(smem + b1o + ee * 2048);
        f32x4 C = {0.f, 0.f, 0.f, 0.f};
        C = __builtin_amdgcn_mfma_f32_16x16x32_f16(a0.v, b0, C, 0, 0, 0);
        C = __builtin_amdgcn_mfma_f32_16x16x32_f16(a1.v, b1, C, 0, 0, 0);

        const float mu = (float)(e0 + ee) * MUSTEP;
#pragma unroll
        for (int reg = 0; reg < 4; ++reg) {
            const float a = C[reg];
#pragma unroll
            for (int p = 0; p < NP; ++p) {
                const float z = ds[reg][p] - mu;
                U[p] = fmaf(a, __builtin_amdgcn_exp2f(-(z * z)), U[p]);
            }
        }
    }

    // ---- phase 4: block reduce -> per-block partial + release flag ----
#pragma unroll
    for (int p = 0; p < NP; ++p) {
        float v = U[p];
        for (int off = 32; off; off >>= 1) v += __shfl_down(v, off, 64);
        U[p] = v;
    }
    __syncthreads();                  // REC/COORD reads done
    float* wred = (float*)(smem + COORD_B);
    if (lane == 0) {
#pragma unroll
        for (int p = 0; p < NP; ++p) wred[wv * 8 + p] = U[p];
    }
    __syncthreads();
    if (t < NP)
        ws[t * NBLK + bid] = wred[t] + wred[8 + t] + wred[16 + t] + wred[24 + t];
    __threadfence();                  // partials visible device-wide
    if (t == 0)
        __hip_atomic_store(&flags[bid], MAGIC, __ATOMIC_RELEASE,
                           __HIP_MEMORY_SCOPE_AGENT);

    // ---- phase 5: block 0 finalizes after all flags set (poison-robust:
    //      flags compared to MAGIC; replays idempotent -- partials identical) --
    if (bid == 0) {
#pragma unroll
        for (int j = 0; j < 4; ++j) {
            const int fb = t * 4 + j;
            while (__hip_atomic_load(&flags[fb], __ATOMIC_ACQUIRE,
                                     __HIP_MEMORY_SCOPE_AGENT) != MAGIC) {}
        }
        __syncthreads();              // whole block has confirmed all 1024
        const int p = t >> 5, j = t & 31;
        float s = 0.f;
#pragma unroll
        for (int k = 0; k < 8; ++k) {
            const float4 v = *(const float4*)&ws[p * NBLK + j * 4 + k * 128];
            s += (v.x + v.y) + (v.z + v.w);
        }
        for (int off = 16; off; off >>= 1) s += __shfl_down(s, off, 32);
        if (j == 0) out[p] = fmaf(s, wq[0], bq[0]);
    }
}

extern "C" void kernel_launch(void* const* d_in, const int* in_sizes, int n_in,
                              void* d_out, int out_size, void* d_ws, size_t ws_size,
                              hipStream_t stream) {
    const float* lig_feat   = (const float*)d_in[0];
    const float* rec_feat   = (const float*)d_in[1];
    const float* lig_coords = (const float*)d_in[2];
    const float* rec_coord  = (const float*)d_in[3];
    const float* weight     = (const float*)d_in[4];
    const float* bias       = (const float*)d_in[5];

    hipLaunchKernelGGL(ff_main, dim3(NBLK), dim3(256), 0, stream,
                       lig_feat, rec_feat, lig_coords, rec_coord,
                       weight, bias, (float*)d_ws, (float*)d_out);
}

// Round 9
// 45.184 us; speedup vs baseline: 2.9177x; 2.9177x over previous
//
#include <hip/hip_runtime.h>

// Problem constants
#define NL 64
#define NR 4096
#define NE 32
#define NF 64
#define NP 8

// RBF math:  rbf = exp(-((d - mu_e)*3.2)^2) = exp2(-(d*DSCALE - e*MUSTEP)^2)
#define DSCALE 3.8435917081166390f   // 3.2 * sqrt(log2(e))
#define MUSTEP 1.2398683f            // (10/31) * DSCALE
#define EPS3   3e-10f                // eps added per coordinate (3 coords)

typedef _Float16 f16x8 __attribute__((ext_vector_type(8)));
typedef __fp16   h16x2 __attribute__((ext_vector_type(2)));   // cvt_pkrtz result
typedef float    f32x4 __attribute__((ext_vector_type(4)));

#define NBLK 1024                    // 256 r-blocks x 4 e-blocks

// COORD LDS: stride 144 B per l (36 dw): float4-aligned; kg-stride (4 l = 576 B
// = 144 dw) == 16 mod 32 banks -> <=2-way aliasing on the broadcast reads.
#define CSTRIDE 144
#define WRED_B  (NL * CSTRIDE)       // 9216: 32-float cross-wave scratch

__global__ __launch_bounds__(256, 4)
void ff_main(const float* __restrict__ lig_feat,    // [64][32][64]
             const float* __restrict__ rec_feat,    // [4096][32][64]
             const float* __restrict__ lig_coords,  // [8][64][3]
             const float* __restrict__ rec_coord,   // [4096][3]
             float* __restrict__ ws)                // [8][NBLK] partials
{
    __shared__ __align__(16) char smem[WRED_B + 128];

    const int t    = threadIdx.x;
    const int bid  = blockIdx.x;
    const int rb   = bid & 255;
    const int eb   = bid >> 8;
    const int r0   = rb * 16;
    const int e0   = eb * 8;
    const int lane = t & 63;
    const int wv   = t >> 6;
    const int l0   = wv * 16;
    const int cn   = lane & 15;       // MFMA col / frag row
    const int kg   = lane >> 4;       // k-group 0..3

    // ---- phase 1: lig coords -> LDS [l: stride 144B][p: 16B] ----
#pragma unroll
    for (int j = 0; j < 6; ++j) {
        const int s = j * 256 + t;            // 0..1535 over [8p][64l][3c]
        const int p = s / 192;
        const int rem = s - p * 192;
        const int l = rem / 3, c = rem - l * 3;
        *(float*)(smem + l * CSTRIDE + p * 16 + c * 4) = lig_coords[s];
    }
    __syncthreads();   // coords ready (only barrier before reduce)

    // ---- phase 2: this lane's 32 distances in registers ----
    const int rr = r0 + cn;
    const float rx = rec_coord[rr * 3 + 0];
    const float ry = rec_coord[rr * 3 + 1];
    const float rz = rec_coord[rr * 3 + 2];
    float ds[4][NP];
#pragma unroll
    for (int reg = 0; reg < 4; ++reg) {
        const int l = l0 + kg * 4 + reg;
#pragma unroll
        for (int p = 0; p < NP; ++p) {
            const float4 lc = *(const float4*)(smem + l * CSTRIDE + p * 16);
            const float dx = lc.x - rx, dy = lc.y - ry, dz = lc.z - rz;
            const float d2 = fmaf(dx, dx, fmaf(dy, dy, fmaf(dz, dz, EPS3)));
            ds[reg][p] = __builtin_amdgcn_sqrtf(d2) * DSCALE;
        }
    }

    // ---- phase 3: main loop, A and B both straight from global (no staging;
    //      64 lanes = 64 distinct (row,k)-chunks of B -> no intra-wave dup) ----
    const float* ligb = &lig_feat[((l0 + cn) * NE + e0) * NF + kg * 8];
    const float* recb = &rec_feat[((r0 + cn) * NE + e0) * NF + kg * 8];

    float U[NP];
#pragma unroll
    for (int p = 0; p < NP; ++p) U[p] = 0.f;

#pragma unroll
    for (int ee = 0; ee < 8; ++ee) {
        const float4 af0 = *(const float4*)(ligb + ee * NF + 0);
        const float4 af1 = *(const float4*)(ligb + ee * NF + 4);
        const float4 af2 = *(const float4*)(ligb + ee * NF + 32);
        const float4 af3 = *(const float4*)(ligb + ee * NF + 36);
        const float4 bf0 = *(const float4*)(recb + ee * NF + 0);
        const float4 bf1 = *(const float4*)(recb + ee * NF + 4);
        const float4 bf2 = *(const float4*)(recb + ee * NF + 32);
        const float4 bf3 = *(const float4*)(recb + ee * NF + 36);
        union { h16x2 h[4]; f16x8 v; } a0, a1, b0, b1;
        a0.h[0] = __builtin_amdgcn_cvt_pkrtz(af0.x, af0.y);
        a0.h[1] = __builtin_amdgcn_cvt_pkrtz(af0.z, af0.w);
        a0.h[2] = __builtin_amdgcn_cvt_pkrtz(af1.x, af1.y);
        a0.h[3] = __builtin_amdgcn_cvt_pkrtz(af1.z, af1.w);
        a1.h[0] = __builtin_amdgcn_cvt_pkrtz(af2.x, af2.y);
        a1.h[1] = __builtin_amdgcn_cvt_pkrtz(af2.z, af2.w);
        a1.h[2] = __builtin_amdgcn_cvt_pkrtz(af3.x, af3.y);
        a1.h[3] = __builtin_amdgcn_cvt_pkrtz(af3.z, af3.w);
        b0.h[0] = __builtin_amdgcn_cvt_pkrtz(bf0.x, bf0.y);
        b0.h[1] = __builtin_amdgcn_cvt_pkrtz(bf0.z, bf0.w);
        b0.h[2] = __builtin_amdgcn_cvt_pkrtz(bf1.x, bf1.y);
        b0.h[3] = __builtin_amdgcn_cvt_pkrtz(bf1.z, bf1.w);
        b1.h[0] = __builtin_amdgcn_cvt_pkrtz(bf2.x, bf2.y);
        b1.h[1] = __builtin_amdgcn_cvt_pkrtz(bf2.z, bf2.w);
        b1.h[2] = __builtin_amdgcn_cvt_pkrtz(bf3.x, bf3.y);
        b1.h[3] = __builtin_amdgcn_cvt_pkrtz(bf3.z, bf3.w);
        f32x4 C = {0.f, 0.f, 0.f, 0.f};
        C = __builtin_amdgcn_mfma_f32_16x16x32_f16(a0.v, b0.v, C, 0, 0, 0);
        C = __builtin_amdgcn_mfma_f32_16x16x32_f16(a1.v, b1.v, C, 0, 0, 0);

        const float mu = (float)(e0 + ee) * MUSTEP;
#pragma unroll
        for (int reg = 0; reg < 4; ++reg) {
            const float a = C[reg];
#pragma unroll
            for (int p = 0; p < NP; ++p) {
                const float z = ds[reg][p] - mu;
                U[p] = fmaf(a, __builtin_amdgcn_exp2f(-(z * z)), U[p]);
            }
        }
    }

    // ---- phase 4: reduce (wave shfl -> cross-wave wred) -> per-block partial --
#pragma unroll
    for (int p = 0; p < NP; ++p) {
        float v = U[p];
        for (int off = 32; off; off >>= 1) v += __shfl_down(v, off, 64);
        U[p] = v;
    }
    float* wred = (float*)(smem + WRED_B);   // disjoint from COORD region
    if (lane == 0) {
#pragma unroll
        for (int p = 0; p < NP; ++p) wred[wv * 8 + p] = U[p];
    }
    __syncthreads();
    if (t < NP)
        ws[t * NBLK + bid] = wred[t] + wred[8 + t] + wred[16 + t] + wred[24 + t];
}

__global__ __launch_bounds__(512)
void ff_fin(const float* __restrict__ ws,
            const float* __restrict__ w,
            const float* __restrict__ b,
            float* __restrict__ out) {
    const int t = threadIdx.x, lane = t & 63, p = t >> 6;
    float s = 0.f;
#pragma unroll
    for (int j = 0; j < NBLK / 256; ++j) {
        const float4 v = *(const float4*)&ws[p * NBLK + j * 256 + lane * 4];
        s += (v.x + v.y) + (v.z + v.w);
    }
    for (int off = 32; off; off >>= 1) s += __shfl_down(s, off, 64);
    if (lane == 0) out[p] = fmaf(s, w[0], b[0]);
}

extern "C" void kernel_launch(void* const* d_in, const int* in_sizes, int n_in,
                              void* d_out, int out_size, void* d_ws, size_t ws_size,
                              hipStream_t stream) {
    const float* lig_feat   = (const float*)d_in[0];
    const float* rec_feat   = (const float*)d_in[1];
    const float* lig_coords = (const float*)d_in[2];
    const float* rec_coord  = (const float*)d_in[3];
    const float* weight     = (const float*)d_in[4];
    const float* bias       = (const float*)d_in[5];
    float* out = (float*)d_out;
    float* ws  = (float*)d_ws;

    hipLaunchKernelGGL(ff_main, dim3(NBLK), dim3(256), 0, stream,
                       lig_feat, rec_feat, lig_coords, rec_coord, ws);
    hipLaunchKernelGGL(ff_fin, dim3(1), dim3(512), 0, stream,
                       ws, weight, bias, out);
}

// Round 10
// 31.894 us; speedup vs baseline: 4.1335x; 1.4167x over previous
//
#include <hip/hip_runtime.h>

// Problem constants
#define NL 64
#define NR 4096
#define NE 32
#define NF 64
#define NP 8

// RBF math:  rbf = exp(-((d - mu_e)*3.2)^2) = exp2(-(d*DSCALE - e*MUSTEP)^2)
#define DSCALE 3.8435917081166390f   // 3.2 * sqrt(log2(e))
#define MUSTEP 1.2398683f            // (10/31) * DSCALE
#define EPS3   3e-10f                // eps added per coordinate (3 coords)

typedef _Float16 f16x8 __attribute__((ext_vector_type(8)));
typedef __fp16   h16x2 __attribute__((ext_vector_type(2)));   // cvt_pkrtz result
typedef float    f32x4 __attribute__((ext_vector_type(4)));

#define NBLK 1024                    // 256 r-blocks x 4 e-blocks
// ws layout: [0, 256KiB) = lig16 fp16[64][32][64] ; [256KiB, +32KiB) = partials
#define PART_B (NL * NE * NF * 2)

// LDS: REC [8e][16r][128B swz] @0 (16384); COORD 64 x 144B @16384 (9216).
// COORD kg-stride 576B == bank 16 mod 32 -> <=2-way (free). wred aliases COORD.
#define REC_B   0
#define COORD_B 16384
#define CSTRIDE 144
#define LDS_SZ  (16384 + 9216)

// ---- prep: lig_feat fp32 -> fp16 table (same [l][e][f] order) --------------
__global__ __launch_bounds__(256)
void ff_prep(const float* __restrict__ lig_feat, void* __restrict__ ws) {
    const int tid = blockIdx.x * 256 + threadIdx.x;   // 32768 float4s
    const float4 v = ((const float4*)lig_feat)[tid];
    union { h16x2 h[2]; uint2 u; } pk;
    pk.h[0] = __builtin_amdgcn_cvt_pkrtz(v.x, v.y);
    pk.h[1] = __builtin_amdgcn_cvt_pkrtz(v.z, v.w);
    ((uint2*)ws)[tid] = pk.u;
}

// ---- main ------------------------------------------------------------------
__global__ __launch_bounds__(256, 2)   // allow ~128 VGPR: (256,4) forced 64+spill
void ff_main(const float* __restrict__ rec_feat,    // [4096][32][64]
             const float* __restrict__ lig_coords,  // [8][64][3]
             const float* __restrict__ rec_coord,   // [4096][3]
             void* __restrict__ ws)
{
    __shared__ __align__(16) char smem[LDS_SZ];

    const int t    = threadIdx.x;
    const int bid  = blockIdx.x;
    const int rb   = bid & 255;
    const int eb   = bid >> 8;
    const int r0   = rb * 16;
    const int e0   = eb * 8;
    const int lane = t & 63;
    const int wv   = t >> 6;
    const int l0   = wv * 16;
    const int cn   = lane & 15;       // MFMA col / frag row
    const int kg   = lane >> 4;       // k-group 0..3

    // ---- issue all REC loads up front (half1 held in regs to mid-loop) ----
    const int srow = t >> 4, sfq = t & 15;
    const int rswz = (8 * sfq) ^ ((srow & 7) << 4);
    const float* recrow = &rec_feat[((r0 + srow) * NE + e0) * NF + sfq * 4];
    float4 h0[4], h1[4];
#pragma unroll
    for (int e = 0; e < 4; ++e) h0[e] = *(const float4*)(recrow + e * NF);
#pragma unroll
    for (int e = 0; e < 4; ++e) h1[e] = *(const float4*)(recrow + (e + 4) * NF);

    // ---- coords -> LDS [l: 144B stride][p: 16B] ----
#pragma unroll
    for (int j = 0; j < 6; ++j) {
        const int s = j * 256 + t;            // 0..1535 over [8p][64l][3c]
        const int p = s / 192;
        const int rem = s - p * 192;
        const int l = rem / 3, c = rem - l * 3;
        *(float*)(smem + COORD_B + l * CSTRIDE + p * 16 + c * 4) = lig_coords[s];
    }
    // ---- write REC half0 ----
#pragma unroll
    for (int e = 0; e < 4; ++e) {
        union { h16x2 h[2]; uint2 u; } pk;
        pk.h[0] = __builtin_amdgcn_cvt_pkrtz(h0[e].x, h0[e].y);
        pk.h[1] = __builtin_amdgcn_cvt_pkrtz(h0[e].z, h0[e].w);
        *(uint2*)(smem + REC_B + e * 2048 + srow * 128 + rswz) = pk.u;
    }
    __syncthreads();   // coords + half0 ready

    // ---- this lane's 32 distances in registers ----
    const int rr = r0 + cn;
    const float rx = rec_coord[rr * 3 + 0];
    const float ry = rec_coord[rr * 3 + 1];
    const float rz = rec_coord[rr * 3 + 2];
    float ds[4][NP];
#pragma unroll
    for (int reg = 0; reg < 4; ++reg) {
        const int l = l0 + kg * 4 + reg;
#pragma unroll
        for (int p = 0; p < NP; ++p) {
            const float4 lc = *(const float4*)(smem + COORD_B + l * CSTRIDE + p * 16);
            const float dx = lc.x - rx, dy = lc.y - ry, dz = lc.z - rz;
            const float d2 = fmaf(dx, dx, fmaf(dy, dy, fmaf(dz, dz, EPS3)));
            ds[reg][p] = __builtin_amdgcn_sqrtf(d2) * DSCALE;
        }
    }

    // ---- main loop: A from fp16 table (2 x uint4/e, depth-1 prefetch),
    //      B from swizzled LDS, half1 staged at ee==3 ----
    const unsigned short* ligb =
        (const unsigned short*)ws + ((l0 + cn) * NE + e0) * NF + kg * 8;
    const int bsw = (cn & 7) << 4;
    const int b0o = REC_B + cn * 128 + ((kg * 16) ^ bsw);
    const int b1o = REC_B + cn * 128 + ((kg * 16 + 64) ^ bsw);

    float U[NP];
#pragma unroll
    for (int p = 0; p < NP; ++p) U[p] = 0.f;

    uint4 an0 = *(const uint4*)(ligb);
    uint4 an1 = *(const uint4*)(ligb + 32);

#pragma unroll
    for (int ee = 0; ee < 8; ++ee) {
        union { uint4 u; f16x8 v; } a0, a1;
        a0.u = an0;
        a1.u = an1;
        if (ee < 7) {                          // depth-1 prefetch
            an0 = *(const uint4*)(ligb + (ee + 1) * NF);
            an1 = *(const uint4*)(ligb + (ee + 1) * NF + 32);
        }
        const f16x8 b0 = *(const f16x8*)(smem + b0o + ee * 2048);
        const f16x8 b1 = *(const f16x8*)(smem + b1o + ee * 2048);
        f32x4 C = {0.f, 0.f, 0.f, 0.f};
        C = __builtin_amdgcn_mfma_f32_16x16x32_f16(a0.v, b0, C, 0, 0, 0);
        C = __builtin_amdgcn_mfma_f32_16x16x32_f16(a1.v, b1, C, 0, 0, 0);

        const float mu = (float)(e0 + ee) * MUSTEP;
#pragma unroll
        for (int reg = 0; reg < 4; ++reg) {
            const float a = C[reg];
#pragma unroll
            for (int p = 0; p < NP; ++p) {
                const float z = ds[reg][p] - mu;
                U[p] = fmaf(a, __builtin_amdgcn_exp2f(-(z * z)), U[p]);
            }
        }

        if (ee == 3) {                         // write REC half1, then fence
#pragma unroll
            for (int e = 0; e < 4; ++e) {
                union { h16x2 h[2]; uint2 u; } pk;
                pk.h[0] = __builtin_amdgcn_cvt_pkrtz(h1[e].x, h1[e].y);
                pk.h[1] = __builtin_amdgcn_cvt_pkrtz(h1[e].z, h1[e].w);
                *(uint2*)(smem + REC_B + (e + 4) * 2048 + srow * 128 + rswz) = pk.u;
            }
            __syncthreads();
        }
    }

    // ---- reduce: wave shfl -> cross-wave (wred aliases dead COORD) ----
#pragma unroll
    for (int p = 0; p < NP; ++p) {
        float v = U[p];
        for (int off = 32; off; off >>= 1) v += __shfl_down(v, off, 64);
        U[p] = v;
    }
    float* wred = (float*)(smem + COORD_B);   // COORD reads all pre-mid-barrier
    if (lane == 0) {
#pragma unroll
        for (int p = 0; p < NP; ++p) wred[wv * 8 + p] = U[p];
    }
    __syncthreads();
    float* part = (float*)((char*)ws + PART_B);
    if (t < NP)
        part[t * NBLK + bid] = wred[t] + wred[8 + t] + wred[16 + t] + wred[24 + t];
}

__global__ __launch_bounds__(512)
void ff_fin(const void* __restrict__ ws,
            const float* __restrict__ w,
            const float* __restrict__ b,
            float* __restrict__ out) {
    const float* part = (const float*)((const char*)ws + PART_B);
    const int t = threadIdx.x, lane = t & 63, p = t >> 6;
    float s = 0.f;
#pragma unroll
    for (int j = 0; j < NBLK / 256; ++j) {
        const float4 v = *(const float4*)&part[p * NBLK + j * 256 + lane * 4];
        s += (v.x + v.y) + (v.z + v.w);
    }
    for (int off = 32; off; off >>= 1) s += __shfl_down(s, off, 64);
    if (lane == 0) out[p] = fmaf(s, w[0], b[0]);
}

extern "C" void kernel_launch(void* const* d_in, const int* in_sizes, int n_in,
                              void* d_out, int out_size, void* d_ws, size_t ws_size,
                              hipStream_t stream) {
    const float* lig_feat   = (const float*)d_in[0];
    const float* rec_feat   = (const float*)d_in[1];
    const float* lig_coords = (const float*)d_in[2];
    const float* rec_coord  = (const float*)d_in[3];
    const float* weight     = (const float*)d_in[4];
    const float* bias       = (const float*)d_in[5];
    float* out = (float*)d_out;

    hipLaunchKernelGGL(ff_prep, dim3(128), dim3(256), 0, stream, lig_feat, d_ws);
    hipLaunchKernelGGL(ff_main, dim3(NBLK), dim3(256), 0, stream,
                       rec_feat, lig_coords, rec_coord, d_ws);
    hipLaunchKernelGGL(ff_fin, dim3(1), dim3(512), 0, stream,
                       d_ws, weight, bias, out);
}